// Round 3
// baseline (277.729 us; speedup 1.0000x reference)
//
#include <hip/hip_runtime.h>
#include <hip/hip_bf16.h>

// out[tgt[i], :] += x[src[i], :] * e[i]   (fp32, D=32)
// CSR-by-target rebuild each call (no cross-call state), then atomic-free
// per-node gather-reduce. Fallback: direct fp32 atomics if ws too small.

#define D_FEAT 32

// ---------------- fallback path (round-2, verified) ----------------
__global__ void zero_out_kernel(float* __restrict__ out, int n) {
    int i = blockIdx.x * blockDim.x + threadIdx.x;
    if (i < n) out[i] = 0.0f;
}

__global__ void scatter_add_kernel(const float* __restrict__ x,
                                   const int* __restrict__ src,
                                   const int* __restrict__ tgt,
                                   const float* __restrict__ e,
                                   float* __restrict__ out,
                                   int n_edges) {
    long long gid    = (long long)blockIdx.x * blockDim.x + threadIdx.x;
    long long total  = (long long)n_edges * D_FEAT;
    if (gid >= total) return;
    int edge = (int)(gid >> 5);
    int f    = (int)(gid & 31);
    float m = x[(long long)src[edge] * D_FEAT + f] * e[edge];
    atomicAdd(&out[(long long)tgt[edge] * D_FEAT + f], m);
}

// ---------------- CSR path ----------------
__global__ void hist_kernel(const int* __restrict__ tgt, int* __restrict__ cnt,
                            int n_edges) {
    int i = blockIdx.x * blockDim.x + threadIdx.x;
    if (i < n_edges) atomicAdd(&cnt[tgt[i]], 1);
}

// per-256-chunk exclusive scan; chunk totals to bsum
__global__ void scan_block_kernel(const int* __restrict__ cnt, int* __restrict__ off,
                                  int* __restrict__ bsum, int n) {
    __shared__ int s[256];
    int i = blockIdx.x * 256 + threadIdx.x;
    int v = (i < n) ? cnt[i] : 0;
    s[threadIdx.x] = v;
    __syncthreads();
    #pragma unroll
    for (int d = 1; d < 256; d <<= 1) {
        int t = (threadIdx.x >= d) ? s[threadIdx.x - d] : 0;
        __syncthreads();
        s[threadIdx.x] += t;
        __syncthreads();
    }
    if (i < n) off[i] = s[threadIdx.x] - v;          // exclusive within chunk
    if (threadIdx.x == 255) bsum[blockIdx.x] = s[255]; // chunk total
}

// single-block exclusive scan of chunk totals (nblk <= 1024)
__global__ void scan_bsum_kernel(int* __restrict__ bsum, int nblk) {
    __shared__ int s[1024];
    int tid = threadIdx.x;
    int v = (tid < nblk) ? bsum[tid] : 0;
    s[tid] = v;
    __syncthreads();
    for (int d = 1; d < 1024; d <<= 1) {
        int t = (tid >= d) ? s[tid - d] : 0;
        __syncthreads();
        s[tid] += t;
        __syncthreads();
    }
    if (tid < nblk) bsum[tid] = s[tid] - v;          // exclusive
}

__global__ void add_base_kernel(int* __restrict__ off, const int* __restrict__ bsum,
                                int n) {
    int i = blockIdx.x * 256 + threadIdx.x;
    if (i < n) off[i] += bsum[blockIdx.x];
}

// scatter records into CSR slots; off[t] advances from start[t] to end[t]
__global__ void scatter_rec_kernel(const int* __restrict__ src,
                                   const int* __restrict__ tgt,
                                   const float* __restrict__ e,
                                   int* __restrict__ off,
                                   int2* __restrict__ rec, int n_edges) {
    int i = blockIdx.x * blockDim.x + threadIdx.x;
    if (i >= n_edges) return;
    int t = tgt[i];
    int pos = atomicAdd(&off[t], 1);
    rec[pos] = make_int2(src[i], __float_as_int(e[i]));
}

// one 32-lane group per node; lane = feature. After scatter, off[t] == end[t],
// and start[t] == (t ? off[t-1] : 0). Writes every node -> no pre-zero needed.
__global__ void gather_kernel(const float* __restrict__ x,
                              const int2* __restrict__ rec,
                              const int* __restrict__ end_ptr,
                              float* __restrict__ out, int n_nodes) {
    int g = blockIdx.x * 8 + (threadIdx.x >> 5);
    if (g >= n_nodes) return;
    int f = threadIdx.x & 31;
    int start = (g == 0) ? 0 : end_ptr[g - 1];
    int end   = end_ptr[g];
    float acc = 0.0f;
    for (int p = start; p < end; ++p) {
        int2 r = rec[p];                              // broadcast across group
        acc += x[(long long)r.x * D_FEAT + f] * __int_as_float(r.y);
    }
    out[(long long)g * D_FEAT + f] = acc;
}

extern "C" void kernel_launch(void* const* d_in, const int* in_sizes, int n_in,
                              void* d_out, int out_size, void* d_ws, size_t ws_size,
                              hipStream_t stream) {
    const float* x = (const float*)d_in[0];
    const int*   a = (const int*)d_in[1];     // [2, n_edges] delivered as int32
    const float* e = (const float*)d_in[2];

    int n_edges = in_sizes[2];
    int n_nodes = out_size / D_FEAT;
    const int* src = a;
    const int* tgt = a + n_edges;
    float* out = (float*)d_out;

    int nblk_scan = (n_nodes + 255) / 256;

    size_t rec_bytes  = (size_t)n_edges * sizeof(int2);
    size_t cnt_bytes  = (size_t)n_nodes * sizeof(int);
    size_t off_bytes  = cnt_bytes;
    size_t bsum_bytes = (size_t)nblk_scan * sizeof(int);
    size_t need = rec_bytes + cnt_bytes + off_bytes + bsum_bytes;

    if (ws_size < need || nblk_scan > 1024) {
        // fallback: direct atomics (verified round 2)
        int threads = 256;
        zero_out_kernel<<<(out_size + threads - 1) / threads, threads, 0, stream>>>(out, out_size);
        long long total = (long long)n_edges * D_FEAT;
        int blocks = (int)((total + threads - 1) / threads);
        scatter_add_kernel<<<blocks, threads, 0, stream>>>(x, src, tgt, e, out, n_edges);
        return;
    }

    char* p = (char*)d_ws;
    int2* rec  = (int2*)p;  p += rec_bytes;   // 8B-aligned first
    int*  cnt  = (int*)p;   p += cnt_bytes;
    int*  off  = (int*)p;   p += off_bytes;
    int*  bsum = (int*)p;

    // all scratch is rederived every call (harness never re-poisons ws)
    hipMemsetAsync(cnt, 0, cnt_bytes, stream);

    hist_kernel<<<(n_edges + 255) / 256, 256, 0, stream>>>(tgt, cnt, n_edges);
    scan_block_kernel<<<nblk_scan, 256, 0, stream>>>(cnt, off, bsum, n_nodes);
    scan_bsum_kernel<<<1, 1024, 0, stream>>>(bsum, nblk_scan);
    add_base_kernel<<<nblk_scan, 256, 0, stream>>>(off, bsum, n_nodes);
    scatter_rec_kernel<<<(n_edges + 255) / 256, 256, 0, stream>>>(src, tgt, e, off, rec, n_edges);
    gather_kernel<<<(n_nodes + 7) / 8, 256, 0, stream>>>(x, rec, off, out, n_nodes);
}